// Round 1
// baseline (632.284 us; speedup 1.0000x reference)
//
#include <hip/hip_runtime.h>

// Sizes (fixed by the reference)
#define NB   64      // batch
#define DCH  256     // channels / embedding dim
#define HW   1024    // 32*32 spatial positions per batch
#define KCB  1024    // codebook entries
#define NPOS 65536   // NB*HW

#define MARGIN 0.02f

// ws layout (bytes):
//   [0,       4096)   esq  float[1024]
//   [4096,  266240)   idx  int[65536]
//   [266240,266304)   flag_cnt (int, padded)
//   [266304,528448)   flag_list int[65536]

__global__ __launch_bounds__(256) void esq_kernel(const float* __restrict__ E,
                                                  float* __restrict__ esq) {
    int k = blockIdx.x * 256 + threadIdx.x;
    float s = 0.f;
#pragma unroll 8
    for (int c = 0; c < DCH; ++c) {
        float e = E[c * KCB + k];
        s = fmaf(e, e, s);
    }
    esq[k] = s;
}

// Coarse pass: per position, argmin_k of (||e_k||^2 - 2 x.e_k), with top-2 for
// near-tie flagging. Block = 256 threads = 16 tk x 16 tp; block tile:
// 128 positions x all K (8 k-tiles of 128), per-thread 8k x 8pos register block.
__global__ __launch_bounds__(256) void vq_main(const float* __restrict__ X,
                                               const float* __restrict__ E,
                                               const float* __restrict__ esq,
                                               int* __restrict__ idx_out,
                                               int* __restrict__ flag_cnt,
                                               int* __restrict__ flag_list) {
    __shared__ float Es[32][128];   // [c-chunk][k-tile]
    __shared__ float Xs[32][128];   // [c-chunk][pos-tile]

    const int tid = threadIdx.x;
    const int tk = tid >> 4;    // 0..15 (k group)
    const int tp = tid & 15;    // 0..15 (pos group)
    const int b = blockIdx.x >> 3;
    const int ptile = blockIdx.x & 7;
    const float* Xb = X + (size_t)b * (DCH * HW) + ptile * 128;

    float b1[8], b2[8];
    int   i1[8];
#pragma unroll
    for (int j = 0; j < 8; ++j) { b1[j] = 3.4e38f; b2[j] = 3.4e38f; i1[j] = 0; }

    for (int kt = 0; kt < 8; ++kt) {
        float acc[8][8];
#pragma unroll
        for (int i = 0; i < 8; ++i)
#pragma unroll
            for (int j = 0; j < 8; ++j) acc[i][j] = 0.f;

        for (int cc = 0; cc < 8; ++cc) {
            // stage 32x128 tiles of E and X (float4, coalesced)
#pragma unroll
            for (int r = 0; r < 4; ++r) {
                int l = tid + 256 * r;           // float4 index 0..1023
                int c = l >> 5;                  // 0..31
                int q = l & 31;                  // 0..31 (float4 within row)
                reinterpret_cast<float4*>(&Es[0][0])[l] =
                    *reinterpret_cast<const float4*>(E + (size_t)(cc * 32 + c) * KCB + kt * 128 + q * 4);
                reinterpret_cast<float4*>(&Xs[0][0])[l] =
                    *reinterpret_cast<const float4*>(Xb + (size_t)(cc * 32 + c) * HW + q * 4);
            }
            __syncthreads();
#pragma unroll 4
            for (int c = 0; c < 32; ++c) {
                float4 e0 = reinterpret_cast<const float4*>(&Es[c][0])[tk * 2 + 0];
                float4 e1 = reinterpret_cast<const float4*>(&Es[c][0])[tk * 2 + 1];
                float4 x0 = reinterpret_cast<const float4*>(&Xs[c][0])[tp * 2 + 0];
                float4 x1 = reinterpret_cast<const float4*>(&Xs[c][0])[tp * 2 + 1];
                float ev[8] = {e0.x, e0.y, e0.z, e0.w, e1.x, e1.y, e1.z, e1.w};
                float xv[8] = {x0.x, x0.y, x0.z, x0.w, x1.x, x1.y, x1.z, x1.w};
#pragma unroll
                for (int i = 0; i < 8; ++i)
#pragma unroll
                    for (int j = 0; j < 8; ++j)
                        acc[i][j] = fmaf(ev[i], xv[j], acc[i][j]);
            }
            __syncthreads();
        }

        // scores + top-2 update (ascending k => first-occurrence on ties)
        int kbase = kt * 128 + tk * 8;
#pragma unroll
        for (int i = 0; i < 8; ++i) {
            float eq = esq[kbase + i];
            int k = kbase + i;
#pragma unroll
            for (int j = 0; j < 8; ++j) {
                float s = fmaf(-2.f, acc[i][j], eq);
                if (s < b1[j]) { b2[j] = b1[j]; b1[j] = s; i1[j] = k; }
                else           { b2[j] = fminf(b2[j], s); }
            }
        }
    }

    // cross-thread reduction over tk (16 threads per position); reuse LDS
    float* rb1 = &Es[0][0];          // 2048 floats
    float* rb2 = &Es[0][0] + 2048;   // 2048 floats
    int*   ri1 = reinterpret_cast<int*>(&Xs[0][0]);  // 2048 ints
    // all threads are past the last barrier and only touch registers since;
    // safe to write (no one reads Es/Xs anymore).
#pragma unroll
    for (int j = 0; j < 8; ++j) {
        int p = tp * 8 + j;
        rb1[p * 16 + tk] = b1[j];
        rb2[p * 16 + tk] = b2[j];
        ri1[p * 16 + tk] = i1[j];
    }
    __syncthreads();
    if (tid < 128) {
        int p = tid;
        float B1 = 3.4e38f, B2 = 3.4e38f;
        int I1 = 0;
        for (int t = 0; t < 16; ++t) {  // ascending tk => ascending k => first-occurrence
            float a1 = rb1[p * 16 + t];
            float a2 = rb2[p * 16 + t];
            int ai = ri1[p * 16 + t];
            if (a1 < B1) { B2 = fminf(B1, a2); B1 = a1; I1 = ai; }
            else         { B2 = fminf(B2, a1); }
        }
        int n = b * HW + ptile * 128 + p;
        idx_out[n] = I1;
        if (B2 - B1 < MARGIN) {
            int s = atomicAdd(flag_cnt, 1);
            flag_list[s] = n;
        }
    }
}

// Exact fp64 re-scan for flagged (near-tie) positions.
__global__ __launch_bounds__(256) void vq_repair(const float* __restrict__ X,
                                                 const float* __restrict__ E,
                                                 int* __restrict__ idx_out,
                                                 const int* __restrict__ flag_cnt,
                                                 const int* __restrict__ flag_list) {
    __shared__ double xs[256];
    __shared__ double rd[256];
    __shared__ int    ri[256];
    const int tid = threadIdx.x;
    int cnt = *flag_cnt;
    for (int f = blockIdx.x; f < cnt; f += gridDim.x) {
        int n = flag_list[f];
        int b = n >> 10, pos = n & 1023;
        xs[tid] = (double)X[(size_t)b * (DCH * HW) + (size_t)tid * HW + pos];
        __syncthreads();
        double best = 1e300;
        int bi = KCB;
        for (int kk = 0; kk < 4; ++kk) {
            int k = kk * 256 + tid;  // hmm: interleaved across threads, lexicographic reduce below fixes ties
            double s = 0.0, eq = 0.0;
#pragma unroll 4
            for (int c = 0; c < DCH; ++c) {
                double e = (double)E[c * KCB + k];
                eq = fma(e, e, eq);
                s  = fma(xs[c], e, s);
            }
            double d = eq - 2.0 * s;
            if (d < best || (d == best && k < bi)) { best = d; bi = k; }
        }
        rd[tid] = best; ri[tid] = bi;
        __syncthreads();
        for (int off = 128; off > 0; off >>= 1) {
            if (tid < off) {
                double od = rd[tid + off]; int oi = ri[tid + off];
                if (od < rd[tid] || (od == rd[tid] && oi < ri[tid])) { rd[tid] = od; ri[tid] = oi; }
            }
            __syncthreads();
        }
        if (tid == 0) idx_out[n] = ri[0];
        __syncthreads();
    }
}

// Gather + write q_ste, quantized (identical forward values) and indices(float).
__global__ __launch_bounds__(256) void vq_write(const float* __restrict__ E,
                                                const int* __restrict__ idx_ws,
                                                float* __restrict__ out0,
                                                float* __restrict__ out1,
                                                float* __restrict__ out2) {
    __shared__ int kk[1024];
    const int tid = threadIdx.x;
    const int b = blockIdx.x >> 3;
    const int cch = blockIdx.x & 7;
#pragma unroll
    for (int r = 0; r < 4; ++r) kk[tid + 256 * r] = idx_ws[b * HW + tid + 256 * r];
    __syncthreads();
    int p0 = tid * 4;
    if (cch == 0) {
        float4 v = {(float)kk[p0], (float)kk[p0 + 1], (float)kk[p0 + 2], (float)kk[p0 + 3]};
        *reinterpret_cast<float4*>(out2 + b * HW + p0) = v;
    }
    int k0 = kk[p0], k1 = kk[p0 + 1], k2 = kk[p0 + 2], k3 = kk[p0 + 3];
    for (int c = cch * 32; c < cch * 32 + 32; ++c) {
        const float* Er = E + (size_t)c * KCB;
        float4 v = {Er[k0], Er[k1], Er[k2], Er[k3]};
        size_t o = (size_t)b * (DCH * HW) + (size_t)c * HW + p0;
        *reinterpret_cast<float4*>(out0 + o) = v;
        *reinterpret_cast<float4*>(out1 + o) = v;
    }
}

extern "C" void kernel_launch(void* const* d_in, const int* in_sizes, int n_in,
                              void* d_out, int out_size, void* d_ws, size_t ws_size,
                              hipStream_t stream) {
    const float* X = (const float*)d_in[0];   // [64,256,32,32] fp32
    const float* E = (const float*)d_in[1];   // [256,1024] fp32
    float* out = (float*)d_out;
    char* ws = (char*)d_ws;

    float* esq  = (float*)ws;
    int* idx    = (int*)(ws + 4096);
    int* fcnt   = (int*)(ws + 266240);
    int* flist  = (int*)(ws + 266304);

    hipMemsetAsync(fcnt, 0, 4, stream);
    esq_kernel<<<4, 256, 0, stream>>>(E, esq);
    vq_main<<<512, 256, 0, stream>>>(X, E, esq, idx, fcnt, flist);
    vq_repair<<<256, 256, 0, stream>>>(X, E, idx, fcnt, flist);
    vq_write<<<512, 256, 0, stream>>>(E, idx,
                                      out,                    // q_ste
                                      out + 16777216,         // quantized
                                      out + 33554432);        // indices (as float)
}